// Round 7
// baseline (55.893 us; speedup 1.0000x reference)
//
#include <hip/hip_runtime.h>

#define B_    64
#define N_    512
#define DIN_  256
#define DOUT_ 256
#define EPS_  1e-5f
#define ROWS_ (B_ * N_)   // 32768
#define NBLK_Y2 512

typedef __attribute__((ext_vector_type(8))) short bf16x8;   // 8 bf16 = 4 VGPRs
typedef __attribute__((ext_vector_type(8))) unsigned short u16x8;
typedef __attribute__((ext_vector_type(4))) float f32x4;
typedef __attribute__((ext_vector_type(4))) short short4v;

__device__ __forceinline__ short f2bf(float f) {
    unsigned u = __builtin_bit_cast(unsigned, f);
    u += 0x7fff + ((u >> 16) & 1);     // round-to-nearest-even
    return (short)(u >> 16);
}

// Fragment order everywhere: [kfrag][efrag(16 cols)][lane(64)][8 shorts].
// Lane l of frag (kf,ef) holds col = ef*16 + (l&15), k = kf*32 + (l>>4)*8 .. +8.

// WTf: W[k][e] -> fragment order.
__global__ __launch_bounds__(256) void wt_cvt(const float* __restrict__ W,
                                              short* __restrict__ WTf) {
    const int c = blockIdx.x * 256 + threadIdx.x;   // 0..8191
    const int kf = c >> 10, ef = (c >> 6) & 15, lp = c & 63;
    const int e = ef * 16 + (lp & 15);
    const int k0 = kf * 32 + (lp >> 4) * 8;
    bf16x8 h;
    #pragma unroll
    for (int j = 0; j < 8; ++j)
        h[j] = f2bf(W[(size_t)(k0 + j) * DOUT_ + e]);
    *(bf16x8*)&WTf[(size_t)c * 8] = h;
}

// xw = x @ W, output in per-batch fragment order xwT[b][kf16][ef16][64][8].
// Barrier-free K-loop: B (WTf, L2-resident) loaded per-wave from global;
// A panel staged once in LDS (frag-linear).
__global__ __launch_bounds__(512, 4) void gemm_xw(const float* __restrict__ X,
                                                  const short* __restrict__ WTf,
                                                  short* __restrict__ xwT) {
    __shared__ __align__(16) short As[8 * 4 * 64 * 8];   // 32 KB
    const int tid = threadIdx.x, wv = tid >> 6, lane = tid & 63;
    const int lrow = lane & 15, lg = lane >> 4;
    const int bid = blockIdx.x;
    const int rowBase = bid * 64;

    // ---- stage A panel once: 64 rows x 256 k, f32 -> bf16, frag-linear ----
    #pragma unroll
    for (int j = 0; j < 4; ++j) {
        int s = tid + j * 512;               // slot 0..2047
        int kf = s >> 8, mf = (s >> 6) & 3, lp = s & 63;
        int row = mf * 16 + (lp & 15);
        int k = kf * 32 + (lp >> 4) * 8;
        const float* src = &X[(size_t)(rowBase + row) * DIN_ + k];
        float4 v0 = *(const float4*)src;
        float4 v1 = *(const float4*)(src + 4);
        bf16x8 h = { f2bf(v0.x), f2bf(v0.y), f2bf(v0.z), f2bf(v0.w),
                     f2bf(v1.x), f2bf(v1.y), f2bf(v1.z), f2bf(v1.w) };
        *(bf16x8*)&As[s * 8] = h;
    }
    __syncthreads();

    // ---- K loop: 8 chunks, 2-deep register prefetch of B, no barriers ----
    const short* b0p = WTf + ((size_t)(wv * 2 + 0) * 64 + lane) * 8;
    const short* b1p = WTf + ((size_t)(wv * 2 + 1) * 64 + lane) * 8;
    bf16x8 bc0 = *(const bf16x8*)(b0p);
    bf16x8 bc1 = *(const bf16x8*)(b1p);
    f32x4 acc[4][2] = {};
    #pragma unroll 2
    for (int c = 0; c < 8; ++c) {
        const int cn = (c + 1 < 8) ? c + 1 : 7;
        bf16x8 bn0 = *(const bf16x8*)(b0p + cn * 8192);
        bf16x8 bn1 = *(const bf16x8*)(b1p + cn * 8192);
        const short* ab = &As[(c * 256 + lane) * 8];
        bf16x8 a0 = *(const bf16x8*)(ab);
        bf16x8 a1 = *(const bf16x8*)(ab + 512);
        bf16x8 a2 = *(const bf16x8*)(ab + 1024);
        bf16x8 a3 = *(const bf16x8*)(ab + 1536);
        acc[0][0] = __builtin_amdgcn_mfma_f32_16x16x32_bf16(a0, bc0, acc[0][0], 0, 0, 0);
        acc[0][1] = __builtin_amdgcn_mfma_f32_16x16x32_bf16(a0, bc1, acc[0][1], 0, 0, 0);
        acc[1][0] = __builtin_amdgcn_mfma_f32_16x16x32_bf16(a1, bc0, acc[1][0], 0, 0, 0);
        acc[1][1] = __builtin_amdgcn_mfma_f32_16x16x32_bf16(a1, bc1, acc[1][1], 0, 0, 0);
        acc[2][0] = __builtin_amdgcn_mfma_f32_16x16x32_bf16(a2, bc0, acc[2][0], 0, 0, 0);
        acc[2][1] = __builtin_amdgcn_mfma_f32_16x16x32_bf16(a2, bc1, acc[2][1], 0, 0, 0);
        acc[3][0] = __builtin_amdgcn_mfma_f32_16x16x32_bf16(a3, bc0, acc[3][0], 0, 0, 0);
        acc[3][1] = __builtin_amdgcn_mfma_f32_16x16x32_bf16(a3, bc1, acc[3][1], 0, 0, 0);
        bc0 = bn0; bc1 = bn1;
    }

    // epilogue: write fragment-order bf16 into this batch's slice
    const int bz = bid >> 3, kfbase = (bid & 7) * 2;
    short* xwb = xwT + (size_t)bz * 131072;
    #pragma unroll
    for (int m = 0; m < 4; ++m)
        #pragma unroll
        for (int nf = 0; nf < 2; ++nf) {
            int kf = kfbase + (m >> 1);
            int ef = wv * 2 + nf;
            int lanep = lrow + 16 * ((m & 1) * 2 + (lg >> 1));
            size_t off = ((size_t)(kf * 16 + ef) * 64 + lanep) * 8 + (lg & 1) * 4;
            short4v o = { f2bf(acc[m][nf][0]), f2bf(acc[m][nf][1]),
                          f2bf(acc[m][nf][2]), f2bf(acc[m][nf][3]) };
            *(short4v*)&xwb[off] = o;
        }
}

// y2[b] = adj[b] @ xw[b] + bias, fused masked stats.
// Barrier-free K-loop: B (xwT slice, XCD-L2-resident) per-wave from global;
// adj panel staged once in LDS (frag-linear, 64 KB).
template <bool BF16Y2>
__global__ __launch_bounds__(512, 4) void gemm_y2(const float* __restrict__ adj,
                                                  const short* __restrict__ xwT,
                                                  const float* __restrict__ bias,
                                                  const float* __restrict__ mask,
                                                  float* __restrict__ outf,
                                                  unsigned short* __restrict__ y2b,
                                                  float* __restrict__ psum,
                                                  float* __restrict__ psumsq,
                                                  float* __restrict__ pcnt) {
    __shared__ __align__(16) short As[16 * 4 * 64 * 8];   // 64 KB
    const int tid = threadIdx.x, wv = tid >> 6, lane = tid & 63;
    const int lrow = lane & 15, lg = lane >> 4;
    const int bid = blockIdx.x;
    const int swz = ((bid & 7) << 6) | (bid >> 3);   // XCD-chunked
    const int bz = swz >> 3, mt = swz & 7;
    const int rowBase = mt * 64;
    const float* A = adj + (size_t)bz * N_ * N_;
    const short* xwb = xwT + (size_t)bz * 131072;

    // ---- stage A panel once: 64 rows x 512 k, f32 -> bf16, frag-linear ----
    #pragma unroll
    for (int j = 0; j < 8; ++j) {
        int s = tid + j * 512;               // slot 0..4095
        int kf = s >> 8, mf = (s >> 6) & 3, lp = s & 63;
        int row = mf * 16 + (lp & 15);
        int k = kf * 32 + (lp >> 4) * 8;
        const float* src = &A[(size_t)(rowBase + row) * N_ + k];
        float4 v0 = *(const float4*)src;
        float4 v1 = *(const float4*)(src + 4);
        bf16x8 h = { f2bf(v0.x), f2bf(v0.y), f2bf(v0.z), f2bf(v0.w),
                     f2bf(v1.x), f2bf(v1.y), f2bf(v1.z), f2bf(v1.w) };
        *(bf16x8*)&As[s * 8] = h;
    }
    __syncthreads();

    // ---- K loop: 16 chunks, 2-deep register prefetch of B, no barriers ----
    const short* b0p = xwb + ((size_t)(wv * 2 + 0) * 64 + lane) * 8;
    const short* b1p = xwb + ((size_t)(wv * 2 + 1) * 64 + lane) * 8;
    bf16x8 bc0 = *(const bf16x8*)(b0p);
    bf16x8 bc1 = *(const bf16x8*)(b1p);
    f32x4 acc[4][2] = {};
    #pragma unroll 2
    for (int c = 0; c < 16; ++c) {
        const int cn = (c + 1 < 16) ? c + 1 : 15;
        bf16x8 bn0 = *(const bf16x8*)(b0p + cn * 8192);
        bf16x8 bn1 = *(const bf16x8*)(b1p + cn * 8192);
        const short* ab = &As[(c * 256 + lane) * 8];
        bf16x8 a0 = *(const bf16x8*)(ab);
        bf16x8 a1 = *(const bf16x8*)(ab + 512);
        bf16x8 a2 = *(const bf16x8*)(ab + 1024);
        bf16x8 a3 = *(const bf16x8*)(ab + 1536);
        acc[0][0] = __builtin_amdgcn_mfma_f32_16x16x32_bf16(a0, bc0, acc[0][0], 0, 0, 0);
        acc[0][1] = __builtin_amdgcn_mfma_f32_16x16x32_bf16(a0, bc1, acc[0][1], 0, 0, 0);
        acc[1][0] = __builtin_amdgcn_mfma_f32_16x16x32_bf16(a1, bc0, acc[1][0], 0, 0, 0);
        acc[1][1] = __builtin_amdgcn_mfma_f32_16x16x32_bf16(a1, bc1, acc[1][1], 0, 0, 0);
        acc[2][0] = __builtin_amdgcn_mfma_f32_16x16x32_bf16(a2, bc0, acc[2][0], 0, 0, 0);
        acc[2][1] = __builtin_amdgcn_mfma_f32_16x16x32_bf16(a2, bc1, acc[2][1], 0, 0, 0);
        acc[3][0] = __builtin_amdgcn_mfma_f32_16x16x32_bf16(a3, bc0, acc[3][0], 0, 0, 0);
        acc[3][1] = __builtin_amdgcn_mfma_f32_16x16x32_bf16(a3, bc1, acc[3][1], 0, 0, 0);
        bc0 = bn0; bc1 = bn1;
    }

    // ---- epilogue: bias + store (bf16 or f32) + masked per-channel stats ----
    float* C = outf + (size_t)bz * N_ * DOUT_;
    unsigned short* Cb = y2b + (size_t)bz * N_ * DOUT_;
    float mv[4][4];
    #pragma unroll
    for (int m = 0; m < 4; ++m)
        #pragma unroll
        for (int r = 0; r < 4; ++r)
            mv[m][r] = mask[bz * N_ + rowBase + m * 16 + lg * 4 + r];
    float sv[2] = {0.f, 0.f}, sq[2] = {0.f, 0.f};
    #pragma unroll
    for (int nf = 0; nf < 2; ++nf) {
        const int col = wv * 32 + nf * 16 + lrow;
        const float bv = bias[col];
        #pragma unroll
        for (int m = 0; m < 4; ++m) {
            const int r0 = rowBase + m * 16 + lg * 4;
            #pragma unroll
            for (int r = 0; r < 4; ++r) {
                float v = acc[m][nf][r] + bv;
                if (BF16Y2)
                    Cb[(size_t)(r0 + r) * DOUT_ + col] = (unsigned short)f2bf(v);
                else
                    C[(size_t)(r0 + r) * DOUT_ + col] = v;
                float vm = v * mv[m][r];
                sv[nf] += vm;
                sq[nf] = fmaf(v, vm, sq[nf]);
            }
        }
    }
    #pragma unroll
    for (int nf = 0; nf < 2; ++nf) {
        sv[nf] += __shfl_xor(sv[nf], 16); sv[nf] += __shfl_xor(sv[nf], 32);
        sq[nf] += __shfl_xor(sq[nf], 16); sq[nf] += __shfl_xor(sq[nf], 32);
    }
    const int pidx = bz * 8 + mt;
    if (lg == 0) {
        #pragma unroll
        for (int nf = 0; nf < 2; ++nf) {
            psum[(size_t)pidx * DOUT_ + wv * 32 + nf * 16 + lrow]   = sv[nf];
            psumsq[(size_t)pidx * DOUT_ + wv * 32 + nf * 16 + lrow] = sq[nf];
        }
    }
    if (wv == 0) {
        float cnt = mask[bz * N_ + rowBase + lane];
        #pragma unroll
        for (int i = 1; i < 64; i <<= 1) cnt += __shfl_xor(cnt, i);
        if (lane == 0) pcnt[pidx] = cnt;
    }
}

__global__ __launch_bounds__(256) void finalize2(const float* __restrict__ psum,
                                                 const float* __restrict__ psumsq,
                                                 const float* __restrict__ pcnt,
                                                 const float* __restrict__ gamma,
                                                 const float* __restrict__ beta,
                                                 float* __restrict__ scsh) {
    const int e = blockIdx.x, t = threadIdx.x;
    float s  = psum[(size_t)t * DOUT_ + e]   + psum[(size_t)(t + 256) * DOUT_ + e];
    float ss = psumsq[(size_t)t * DOUT_ + e] + psumsq[(size_t)(t + 256) * DOUT_ + e];
    float n  = pcnt[t] + pcnt[t + 256];
    #pragma unroll
    for (int i = 1; i < 64; i <<= 1) {
        s += __shfl_xor(s, i); ss += __shfl_xor(ss, i); n += __shfl_xor(n, i);
    }
    __shared__ float red[3][4];
    const int wv = t >> 6;
    if ((t & 63) == 0) { red[0][wv] = s; red[1][wv] = ss; red[2][wv] = n; }
    __syncthreads();
    if (t == 0) {
        s  = red[0][0] + red[0][1] + red[0][2] + red[0][3];
        ss = red[1][0] + red[1][1] + red[1][2] + red[1][3];
        n  = red[2][0] + red[2][1] + red[2][2] + red[2][3];
        float mean = s / n;
        float var = ss / n - mean * mean;
        float sc = rsqrtf(var + EPS_) * gamma[e];
        scsh[e] = sc;
        scsh[DOUT_ + e] = beta[e] - mean * sc;
    }
}

// out = relu((bf16(y2)*scale + shift) * mask), bf16 in -> f32 out
__global__ __launch_bounds__(256) void norm_relu_bf(const unsigned short* __restrict__ y2b,
                                                    const float* __restrict__ mask,
                                                    const float* __restrict__ scsh,
                                                    float* __restrict__ out) {
    const int nq = ROWS_ * (DOUT_ / 8);
    for (int q = blockIdx.x * blockDim.x + threadIdx.x; q < nq;
         q += gridDim.x * blockDim.x) {
        int e8 = (q & 31) * 8;
        int r = q >> 5;
        float m = mask[r];
        u16x8 uv = *(const u16x8*)&y2b[(size_t)q * 8];
        float4 sc0 = *(const float4*)&scsh[e8];
        float4 sc1 = *(const float4*)&scsh[e8 + 4];
        float4 sh0 = *(const float4*)&scsh[DOUT_ + e8];
        float4 sh1 = *(const float4*)&scsh[DOUT_ + e8 + 4];
        float4 o0, o1;
        #pragma unroll
        for (int j = 0; j < 4; ++j) {
            float f = __builtin_bit_cast(float, (unsigned)uv[j] << 16);
            (&o0.x)[j] = fmaxf(fmaf(f, (&sc0.x)[j], (&sh0.x)[j]) * m, 0.f);
        }
        #pragma unroll
        for (int j = 0; j < 4; ++j) {
            float f = __builtin_bit_cast(float, (unsigned)uv[j + 4] << 16);
            (&o1.x)[j] = fmaxf(fmaf(f, (&sc1.x)[j], (&sh1.x)[j]) * m, 0.f);
        }
        *(float4*)&out[(size_t)q * 8] = o0;
        *(float4*)&out[(size_t)q * 8 + 4] = o1;
    }
}

// fallback: f32 y2 in place
__global__ __launch_bounds__(256) void norm_relu_f32(float* __restrict__ y2,
                                                     const float* __restrict__ mask,
                                                     const float* __restrict__ scsh) {
    const int nq = ROWS_ * (DOUT_ / 4);
    for (int q = blockIdx.x * blockDim.x + threadIdx.x; q < nq;
         q += gridDim.x * blockDim.x) {
        int e4 = (q & 63) * 4;
        int r = q >> 6;
        float m = mask[r];
        float4 v  = *(float4*)&y2[(size_t)q * 4];
        float4 sc = *(const float4*)&scsh[e4];
        float4 sh = *(const float4*)&scsh[DOUT_ + e4];
        v.x = fmaxf(fmaf(v.x, sc.x, sh.x) * m, 0.f);
        v.y = fmaxf(fmaf(v.y, sc.y, sh.y) * m, 0.f);
        v.z = fmaxf(fmaf(v.z, sc.z, sh.z) * m, 0.f);
        v.w = fmaxf(fmaf(v.w, sc.w, sh.w) * m, 0.f);
        *(float4*)&y2[(size_t)q * 4] = v;
    }
}

extern "C" void kernel_launch(void* const* d_in, const int* in_sizes, int n_in,
                              void* d_out, int out_size, void* d_ws, size_t ws_size,
                              hipStream_t stream) {
    const float* x      = (const float*)d_in[0];
    const float* adj    = (const float*)d_in[1];
    const float* mask   = (const float*)d_in[2];
    const float* weight = (const float*)d_in[3];
    const float* bias   = (const float*)d_in[4];
    const float* gamma  = (const float*)d_in[5];
    const float* beta   = (const float*)d_in[6];
    float* out = (float*)d_out;

    const size_t xw_elems = (size_t)DOUT_ * ROWS_;          // shorts
    const size_t need_bf = 131072 + xw_elems * 2 * 2 +       // WTf + xwT + y2b
                           (size_t)NBLK_Y2 * DOUT_ * 4 * 2 + NBLK_Y2 * 4 + 2048 + 64;
    const bool use_bf = ws_size >= need_bf;

    short* WTf    = (short*)d_ws;                            // 128 KB
    short* xwT    = WTf + 256 * 256;                         // 16.8 MB
    unsigned short* y2b = (unsigned short*)(xwT + xw_elems); // 16.8 MB (bf path)
    float* psum   = use_bf ? (float*)(y2b + xw_elems) : (float*)(y2b);
    float* psumsq = psum + NBLK_Y2 * DOUT_;
    float* pcnt   = psumsq + NBLK_Y2 * DOUT_;
    float* scsh   = pcnt + NBLK_Y2;

    wt_cvt<<<32, 256, 0, stream>>>(weight, WTf);
    gemm_xw<<<512, 512, 0, stream>>>(x, WTf, xwT);
    if (use_bf) {
        gemm_y2<true><<<NBLK_Y2, 512, 0, stream>>>(adj, xwT, bias, mask, out, y2b,
                                                   psum, psumsq, pcnt);
        finalize2<<<256, 256, 0, stream>>>(psum, psumsq, pcnt, gamma, beta, scsh);
        norm_relu_bf<<<2048, 256, 0, stream>>>(y2b, mask, scsh, out);
    } else {
        gemm_y2<false><<<NBLK_Y2, 512, 0, stream>>>(adj, xwT, bias, mask, out, y2b,
                                                    psum, psumsq, pcnt);
        finalize2<<<256, 256, 0, stream>>>(psum, psumsq, pcnt, gamma, beta, scsh);
        norm_relu_f32<<<2048, 256, 0, stream>>>(out, mask, scsh);
    }
}

// Round 8
// 55.523 us; speedup vs baseline: 1.0067x; 1.0067x over previous
//
#include <hip/hip_runtime.h>

#define B_    64
#define N_    512
#define DIN_  256
#define DOUT_ 256
#define EPS_  1e-5f
#define ROWS_ (B_ * N_)   // 32768
#define NBLK_Y2 512

typedef __attribute__((ext_vector_type(8))) short bf16x8;   // 8 bf16 = 4 VGPRs
typedef __attribute__((ext_vector_type(8))) unsigned short u16x8;
typedef __attribute__((ext_vector_type(4))) float f32x4;
typedef __attribute__((ext_vector_type(4))) short short4v;

__device__ __forceinline__ short f2bf(float f) {
    unsigned u = __builtin_bit_cast(unsigned, f);
    u += 0x7fff + ((u >> 16) & 1);     // round-to-nearest-even
    return (short)(u >> 16);
}

// Fragment order everywhere: [kfrag][efrag(16 cols)][lane(64)][8 shorts].
// Lane l of frag (kf,ef) holds col = ef*16 + (l&15), k = kf*32 + (l>>4)*8 .. +8.

// WTf: W[k][e] -> fragment order.
__global__ __launch_bounds__(256) void wt_cvt(const float* __restrict__ W,
                                              short* __restrict__ WTf) {
    const int c = blockIdx.x * 256 + threadIdx.x;   // 0..8191
    const int kf = c >> 10, ef = (c >> 6) & 15, lp = c & 63;
    const int e = ef * 16 + (lp & 15);
    const int k0 = kf * 32 + (lp >> 4) * 8;
    bf16x8 h;
    #pragma unroll
    for (int j = 0; j < 8; ++j)
        h[j] = f2bf(W[(size_t)(k0 + j) * DOUT_ + e]);
    *(bf16x8*)&WTf[(size_t)c * 8] = h;
}

// xw = x @ W, output in per-batch fragment order xwT[b][kf16][ef16][64][8].
// WRITER-XCD ALIGNMENT: row-tile rt chosen so the block writing batch wz
// sits on XCD wz>>3 — the same XCD where gemm_y2's readers of wz are pinned.
// rt = (q*8 + m)*8 + s with q=bid&7 (XCD), m=(bid>>3)&7, s=bid>>6  (bijective)
__global__ __launch_bounds__(512, 4) void gemm_xw(const float* __restrict__ X,
                                                  const short* __restrict__ WTf,
                                                  short* __restrict__ xwT) {
    __shared__ __align__(16) short As[8 * 4 * 64 * 8];   // 32 KB
    const int tid = threadIdx.x, wv = tid >> 6, lane = tid & 63;
    const int lrow = lane & 15, lg = lane >> 4;
    const int bid = blockIdx.x;
    const int rt = ((bid & 7) * 8 + ((bid >> 3) & 7)) * 8 + (bid >> 6);
    const int rowBase = rt * 64;

    // ---- stage A panel once: 64 rows x 256 k, f32 -> bf16, frag-linear ----
    #pragma unroll
    for (int j = 0; j < 4; ++j) {
        int s = tid + j * 512;               // slot 0..2047
        int kf = s >> 8, mf = (s >> 6) & 3, lp = s & 63;
        int row = mf * 16 + (lp & 15);
        int k = kf * 32 + (lp >> 4) * 8;
        const float* src = &X[(size_t)(rowBase + row) * DIN_ + k];
        float4 v0 = *(const float4*)src;
        float4 v1 = *(const float4*)(src + 4);
        bf16x8 h = { f2bf(v0.x), f2bf(v0.y), f2bf(v0.z), f2bf(v0.w),
                     f2bf(v1.x), f2bf(v1.y), f2bf(v1.z), f2bf(v1.w) };
        *(bf16x8*)&As[s * 8] = h;
    }
    __syncthreads();

    // ---- K loop: 8 chunks, 2-deep register prefetch of B, no barriers ----
    const short* b0p = WTf + ((size_t)(wv * 2 + 0) * 64 + lane) * 8;
    const short* b1p = WTf + ((size_t)(wv * 2 + 1) * 64 + lane) * 8;
    bf16x8 bc0 = *(const bf16x8*)(b0p);
    bf16x8 bc1 = *(const bf16x8*)(b1p);
    f32x4 acc[4][2] = {};
    #pragma unroll 2
    for (int c = 0; c < 8; ++c) {
        const int cn = (c + 1 < 8) ? c + 1 : 7;
        bf16x8 bn0 = *(const bf16x8*)(b0p + cn * 8192);
        bf16x8 bn1 = *(const bf16x8*)(b1p + cn * 8192);
        const short* ab = &As[(c * 256 + lane) * 8];
        bf16x8 a0 = *(const bf16x8*)(ab);
        bf16x8 a1 = *(const bf16x8*)(ab + 512);
        bf16x8 a2 = *(const bf16x8*)(ab + 1024);
        bf16x8 a3 = *(const bf16x8*)(ab + 1536);
        acc[0][0] = __builtin_amdgcn_mfma_f32_16x16x32_bf16(a0, bc0, acc[0][0], 0, 0, 0);
        acc[0][1] = __builtin_amdgcn_mfma_f32_16x16x32_bf16(a0, bc1, acc[0][1], 0, 0, 0);
        acc[1][0] = __builtin_amdgcn_mfma_f32_16x16x32_bf16(a1, bc0, acc[1][0], 0, 0, 0);
        acc[1][1] = __builtin_amdgcn_mfma_f32_16x16x32_bf16(a1, bc1, acc[1][1], 0, 0, 0);
        acc[2][0] = __builtin_amdgcn_mfma_f32_16x16x32_bf16(a2, bc0, acc[2][0], 0, 0, 0);
        acc[2][1] = __builtin_amdgcn_mfma_f32_16x16x32_bf16(a2, bc1, acc[2][1], 0, 0, 0);
        acc[3][0] = __builtin_amdgcn_mfma_f32_16x16x32_bf16(a3, bc0, acc[3][0], 0, 0, 0);
        acc[3][1] = __builtin_amdgcn_mfma_f32_16x16x32_bf16(a3, bc1, acc[3][1], 0, 0, 0);
        bc0 = bn0; bc1 = bn1;
    }

    // epilogue: write fragment-order bf16 into this batch's slice (local XCD L2)
    const int bz = rt >> 3, kfbase = (rt & 7) * 2;
    short* xwb = xwT + (size_t)bz * 131072;
    #pragma unroll
    for (int m = 0; m < 4; ++m)
        #pragma unroll
        for (int nf = 0; nf < 2; ++nf) {
            int kf = kfbase + (m >> 1);
            int ef = wv * 2 + nf;
            int lanep = lrow + 16 * ((m & 1) * 2 + (lg >> 1));
            size_t off = ((size_t)(kf * 16 + ef) * 64 + lanep) * 8 + (lg & 1) * 4;
            short4v o = { f2bf(acc[m][nf][0]), f2bf(acc[m][nf][1]),
                          f2bf(acc[m][nf][2]), f2bf(acc[m][nf][3]) };
            *(short4v*)&xwb[off] = o;
        }
}

// y2[b] = adj[b] @ xw[b] + bias, fused masked stats.
// Barrier-free K-loop; B per-wave from global (now local-XCD L2);
// 4-deep register prefetch, fully unrolled (static indices).
template <bool BF16Y2>
__global__ __launch_bounds__(512, 4) void gemm_y2(const float* __restrict__ adj,
                                                  const short* __restrict__ xwT,
                                                  const float* __restrict__ bias,
                                                  const float* __restrict__ mask,
                                                  float* __restrict__ outf,
                                                  unsigned short* __restrict__ y2b,
                                                  float* __restrict__ psum,
                                                  float* __restrict__ psumsq,
                                                  float* __restrict__ pcnt) {
    __shared__ __align__(16) short As[16 * 4 * 64 * 8];   // 64 KB
    const int tid = threadIdx.x, wv = tid >> 6, lane = tid & 63;
    const int lrow = lane & 15, lg = lane >> 4;
    const int bid = blockIdx.x;
    const int swz = ((bid & 7) << 6) | (bid >> 3);   // XCD-chunked
    const int bz = swz >> 3, mt = swz & 7;           // batch bz on XCD bz>>3
    const int rowBase = mt * 64;
    const float* A = adj + (size_t)bz * N_ * N_;
    const short* xwb = xwT + (size_t)bz * 131072;

    // ---- stage A panel once: 64 rows x 512 k, f32 -> bf16, frag-linear ----
    #pragma unroll
    for (int j = 0; j < 8; ++j) {
        int s = tid + j * 512;               // slot 0..4095
        int kf = s >> 8, mf = (s >> 6) & 3, lp = s & 63;
        int row = mf * 16 + (lp & 15);
        int k = kf * 32 + (lp >> 4) * 8;
        const float* src = &A[(size_t)(rowBase + row) * N_ + k];
        float4 v0 = *(const float4*)src;
        float4 v1 = *(const float4*)(src + 4);
        bf16x8 h = { f2bf(v0.x), f2bf(v0.y), f2bf(v0.z), f2bf(v0.w),
                     f2bf(v1.x), f2bf(v1.y), f2bf(v1.z), f2bf(v1.w) };
        *(bf16x8*)&As[s * 8] = h;
    }
    __syncthreads();

    // ---- K loop: 16 chunks, 4-deep register prefetch of B, no barriers ----
    const short* b0p = xwb + ((size_t)(wv * 2 + 0) * 64 + lane) * 8;
    const short* b1p = xwb + ((size_t)(wv * 2 + 1) * 64 + lane) * 8;
    bf16x8 bpre[4][2];
    #pragma unroll
    for (int p = 0; p < 3; ++p) {
        bpre[p][0] = *(const bf16x8*)(b0p + p * 8192);
        bpre[p][1] = *(const bf16x8*)(b1p + p * 8192);
    }
    f32x4 acc[4][2] = {};
    #pragma unroll
    for (int c = 0; c < 16; ++c) {           // fully unrolled: static bpre idx
        const int cn = (c + 3 < 16) ? c + 3 : 15;
        bpre[(c + 3) & 3][0] = *(const bf16x8*)(b0p + cn * 8192);
        bpre[(c + 3) & 3][1] = *(const bf16x8*)(b1p + cn * 8192);
        const short* ab = &As[(c * 256 + lane) * 8];
        bf16x8 a0 = *(const bf16x8*)(ab);
        bf16x8 a1 = *(const bf16x8*)(ab + 512);
        bf16x8 a2 = *(const bf16x8*)(ab + 1024);
        bf16x8 a3 = *(const bf16x8*)(ab + 1536);
        bf16x8 bc0 = bpre[c & 3][0];
        bf16x8 bc1 = bpre[c & 3][1];
        acc[0][0] = __builtin_amdgcn_mfma_f32_16x16x32_bf16(a0, bc0, acc[0][0], 0, 0, 0);
        acc[0][1] = __builtin_amdgcn_mfma_f32_16x16x32_bf16(a0, bc1, acc[0][1], 0, 0, 0);
        acc[1][0] = __builtin_amdgcn_mfma_f32_16x16x32_bf16(a1, bc0, acc[1][0], 0, 0, 0);
        acc[1][1] = __builtin_amdgcn_mfma_f32_16x16x32_bf16(a1, bc1, acc[1][1], 0, 0, 0);
        acc[2][0] = __builtin_amdgcn_mfma_f32_16x16x32_bf16(a2, bc0, acc[2][0], 0, 0, 0);
        acc[2][1] = __builtin_amdgcn_mfma_f32_16x16x32_bf16(a2, bc1, acc[2][1], 0, 0, 0);
        acc[3][0] = __builtin_amdgcn_mfma_f32_16x16x32_bf16(a3, bc0, acc[3][0], 0, 0, 0);
        acc[3][1] = __builtin_amdgcn_mfma_f32_16x16x32_bf16(a3, bc1, acc[3][1], 0, 0, 0);
    }

    // ---- epilogue: bias + store (bf16 or f32) + masked per-channel stats ----
    float* C = outf + (size_t)bz * N_ * DOUT_;
    unsigned short* Cb = y2b + (size_t)bz * N_ * DOUT_;
    float mv[4][4];
    #pragma unroll
    for (int m = 0; m < 4; ++m)
        #pragma unroll
        for (int r = 0; r < 4; ++r)
            mv[m][r] = mask[bz * N_ + rowBase + m * 16 + lg * 4 + r];
    float sv[2] = {0.f, 0.f}, sq[2] = {0.f, 0.f};
    #pragma unroll
    for (int nf = 0; nf < 2; ++nf) {
        const int col = wv * 32 + nf * 16 + lrow;
        const float bv = bias[col];
        #pragma unroll
        for (int m = 0; m < 4; ++m) {
            const int r0 = rowBase + m * 16 + lg * 4;
            #pragma unroll
            for (int r = 0; r < 4; ++r) {
                float v = acc[m][nf][r] + bv;
                if (BF16Y2)
                    Cb[(size_t)(r0 + r) * DOUT_ + col] = (unsigned short)f2bf(v);
                else
                    C[(size_t)(r0 + r) * DOUT_ + col] = v;
                float vm = v * mv[m][r];
                sv[nf] += vm;
                sq[nf] = fmaf(v, vm, sq[nf]);
            }
        }
    }
    #pragma unroll
    for (int nf = 0; nf < 2; ++nf) {
        sv[nf] += __shfl_xor(sv[nf], 16); sv[nf] += __shfl_xor(sv[nf], 32);
        sq[nf] += __shfl_xor(sq[nf], 16); sq[nf] += __shfl_xor(sq[nf], 32);
    }
    const int pidx = bz * 8 + mt;
    if (lg == 0) {
        #pragma unroll
        for (int nf = 0; nf < 2; ++nf) {
            psum[(size_t)pidx * DOUT_ + wv * 32 + nf * 16 + lrow]   = sv[nf];
            psumsq[(size_t)pidx * DOUT_ + wv * 32 + nf * 16 + lrow] = sq[nf];
        }
    }
    if (wv == 0) {
        float cnt = mask[bz * N_ + rowBase + lane];
        #pragma unroll
        for (int i = 1; i < 64; i <<= 1) cnt += __shfl_xor(cnt, i);
        if (lane == 0) pcnt[pidx] = cnt;
    }
}

__global__ __launch_bounds__(256) void finalize2(const float* __restrict__ psum,
                                                 const float* __restrict__ psumsq,
                                                 const float* __restrict__ pcnt,
                                                 const float* __restrict__ gamma,
                                                 const float* __restrict__ beta,
                                                 float* __restrict__ scsh) {
    const int e = blockIdx.x, t = threadIdx.x;
    float s  = psum[(size_t)t * DOUT_ + e]   + psum[(size_t)(t + 256) * DOUT_ + e];
    float ss = psumsq[(size_t)t * DOUT_ + e] + psumsq[(size_t)(t + 256) * DOUT_ + e];
    float n  = pcnt[t] + pcnt[t + 256];
    #pragma unroll
    for (int i = 1; i < 64; i <<= 1) {
        s += __shfl_xor(s, i); ss += __shfl_xor(ss, i); n += __shfl_xor(n, i);
    }
    __shared__ float red[3][4];
    const int wv = t >> 6;
    if ((t & 63) == 0) { red[0][wv] = s; red[1][wv] = ss; red[2][wv] = n; }
    __syncthreads();
    if (t == 0) {
        s  = red[0][0] + red[0][1] + red[0][2] + red[0][3];
        ss = red[1][0] + red[1][1] + red[1][2] + red[1][3];
        n  = red[2][0] + red[2][1] + red[2][2] + red[2][3];
        float mean = s / n;
        float var = ss / n - mean * mean;
        float sc = rsqrtf(var + EPS_) * gamma[e];
        scsh[e] = sc;
        scsh[DOUT_ + e] = beta[e] - mean * sc;
    }
}

// out = relu((bf16(y2)*scale + shift) * mask), bf16 in -> f32 out
__global__ __launch_bounds__(256) void norm_relu_bf(const unsigned short* __restrict__ y2b,
                                                    const float* __restrict__ mask,
                                                    const float* __restrict__ scsh,
                                                    float* __restrict__ out) {
    const int nq = ROWS_ * (DOUT_ / 8);
    for (int q = blockIdx.x * blockDim.x + threadIdx.x; q < nq;
         q += gridDim.x * blockDim.x) {
        int e8 = (q & 31) * 8;
        int r = q >> 5;
        float m = mask[r];
        u16x8 uv = *(const u16x8*)&y2b[(size_t)q * 8];
        float4 sc0 = *(const float4*)&scsh[e8];
        float4 sc1 = *(const float4*)&scsh[e8 + 4];
        float4 sh0 = *(const float4*)&scsh[DOUT_ + e8];
        float4 sh1 = *(const float4*)&scsh[DOUT_ + e8 + 4];
        float4 o0, o1;
        #pragma unroll
        for (int j = 0; j < 4; ++j) {
            float f = __builtin_bit_cast(float, (unsigned)uv[j] << 16);
            (&o0.x)[j] = fmaxf(fmaf(f, (&sc0.x)[j], (&sh0.x)[j]) * m, 0.f);
        }
        #pragma unroll
        for (int j = 0; j < 4; ++j) {
            float f = __builtin_bit_cast(float, (unsigned)uv[j + 4] << 16);
            (&o1.x)[j] = fmaxf(fmaf(f, (&sc1.x)[j], (&sh1.x)[j]) * m, 0.f);
        }
        *(float4*)&out[(size_t)q * 8] = o0;
        *(float4*)&out[(size_t)q * 8 + 4] = o1;
    }
}

// fallback: f32 y2 in place
__global__ __launch_bounds__(256) void norm_relu_f32(float* __restrict__ y2,
                                                     const float* __restrict__ mask,
                                                     const float* __restrict__ scsh) {
    const int nq = ROWS_ * (DOUT_ / 4);
    for (int q = blockIdx.x * blockDim.x + threadIdx.x; q < nq;
         q += gridDim.x * blockDim.x) {
        int e4 = (q & 63) * 4;
        int r = q >> 6;
        float m = mask[r];
        float4 v  = *(float4*)&y2[(size_t)q * 4];
        float4 sc = *(const float4*)&scsh[e4];
        float4 sh = *(const float4*)&scsh[DOUT_ + e4];
        v.x = fmaxf(fmaf(v.x, sc.x, sh.x) * m, 0.f);
        v.y = fmaxf(fmaf(v.y, sc.y, sh.y) * m, 0.f);
        v.z = fmaxf(fmaf(v.z, sc.z, sh.z) * m, 0.f);
        v.w = fmaxf(fmaf(v.w, sc.w, sh.w) * m, 0.f);
        *(float4*)&y2[(size_t)q * 4] = v;
    }
}

extern "C" void kernel_launch(void* const* d_in, const int* in_sizes, int n_in,
                              void* d_out, int out_size, void* d_ws, size_t ws_size,
                              hipStream_t stream) {
    const float* x      = (const float*)d_in[0];
    const float* adj    = (const float*)d_in[1];
    const float* mask   = (const float*)d_in[2];
    const float* weight = (const float*)d_in[3];
    const float* bias   = (const float*)d_in[4];
    const float* gamma  = (const float*)d_in[5];
    const float* beta   = (const float*)d_in[6];
    float* out = (float*)d_out;

    const size_t xw_elems = (size_t)DOUT_ * ROWS_;          // shorts
    const size_t need_bf = 131072 + xw_elems * 2 * 2 +       // WTf + xwT + y2b
                           (size_t)NBLK_Y2 * DOUT_ * 4 * 2 + NBLK_Y2 * 4 + 2048 + 64;
    const bool use_bf = ws_size >= need_bf;

    short* WTf    = (short*)d_ws;                            // 128 KB
    short* xwT    = WTf + 256 * 256;                         // 16.8 MB
    unsigned short* y2b = (unsigned short*)(xwT + xw_elems); // 16.8 MB (bf path)
    float* psum   = use_bf ? (float*)(y2b + xw_elems) : (float*)(y2b);
    float* psumsq = psum + NBLK_Y2 * DOUT_;
    float* pcnt   = psumsq + NBLK_Y2 * DOUT_;
    float* scsh   = pcnt + NBLK_Y2;

    wt_cvt<<<32, 256, 0, stream>>>(weight, WTf);
    gemm_xw<<<512, 512, 0, stream>>>(x, WTf, xwT);
    if (use_bf) {
        gemm_y2<true><<<NBLK_Y2, 512, 0, stream>>>(adj, xwT, bias, mask, out, y2b,
                                                   psum, psumsq, pcnt);
        finalize2<<<256, 256, 0, stream>>>(psum, psumsq, pcnt, gamma, beta, scsh);
        norm_relu_bf<<<2048, 256, 0, stream>>>(y2b, mask, scsh, out);
    } else {
        gemm_y2<false><<<NBLK_Y2, 512, 0, stream>>>(adj, xwT, bias, mask, out, y2b,
                                                    psum, psumsq, pcnt);
        finalize2<<<256, 256, 0, stream>>>(psum, psumsq, pcnt, gamma, beta, scsh);
        norm_relu_f32<<<2048, 256, 0, stream>>>(out, mask, scsh);
    }
}